// Round 3
// baseline (333.301 us; speedup 1.0000x reference)
//
#include <hip/hip_runtime.h>

// ---------------------------------------------------------------------------
// MatryoshkaAttention on MI355X (gfx950), bf16 MFMA pipeline. Round 9.
//
// R9 = R8 resubmit (rounds 1-2 were infra failures at container acquire/push;
// no kernel verdict either time; round-0 timing already showed the push path
// limping at 1258 s for 66 MB). Kernel statically re-audited: barriers
// wave-uniform, vmcnt FIFO exact, zero OOB, wave-uniform LDS staging bases.
//
//  - k_gemm1: QKV GEMM as 256x256 tile, BK=32, 8 waves, TRIPLE-buffered LDS
//    (96 KiB) with counted s_waitcnt vmcnt(4) once per K-tile (never a
//    vmcnt(0) drain mid-loop), per-phase {ds_read || global_load_lds ||
//    barrier || setprio(1) + 16 MFMA + setprio(0)}.
//    Pipeline invariant: computing tile t (buf t%3) while t+1 is landed and
//    t+2 streams into buf (t+2)%3 (free: its readers finished before the
//    boundary barrier of t-1).
//    Grid: 288 blocks, LPT (240 Keff=2048 first, 32 Keff=1024, 16 Keff=256).
//  - k_gemm_bt kept for MODE 1 (output GEMM) only.
// ---------------------------------------------------------------------------

typedef short bf16x8 __attribute__((ext_vector_type(8)));
typedef float floatx4 __attribute__((ext_vector_type(4)));

__device__ __forceinline__ unsigned short f2bf(float f) {
  unsigned u = __builtin_bit_cast(unsigned, f);
  u += 0x7fffu + ((u >> 16) & 1u);           // RNE
  return (unsigned short)(u >> 16);
}

__device__ __forceinline__ void gload_lds16(const unsigned short* g, unsigned short* l) {
  __builtin_amdgcn_global_load_lds((const __attribute__((address_space(1))) unsigned int*)g,
                                   (__attribute__((address_space(3))) unsigned int*)l, 16, 0, 0);
}

// ---------------- 1. fused prep: cvt_x | pack_qkv(+corr) | pack_o ----------
// blocks [0,8192): x->bf16 ; [8192,17408): W_QKV pack ; [17408,20480): W_O.
__global__ __launch_bounds__(256) void k_prep(
    const float* __restrict__ x, unsigned short* __restrict__ X16,
    const float* __restrict__ WQ, const float* __restrict__ WK, const float* __restrict__ WV,
    const float* __restrict__ FK0, const float* __restrict__ PK0,
    const float* __restrict__ FV0, const float* __restrict__ PV0,
    const float* __restrict__ FK1, const float* __restrict__ PK1,
    const float* __restrict__ FV1, const float* __restrict__ PV1,
    unsigned short* __restrict__ WTQKV,
    const float* __restrict__ WO, unsigned short* __restrict__ WTO) {
  __shared__ float tile[32][33];
  __shared__ float Fs[32][9];
  __shared__ float Ps[8][32];
  const int bid = blockIdx.x;
  const int tid = threadIdx.x;
  if (bid < 8192) {                       // ---- x -> bf16 (float4 per thread)
    int i = bid * 256 + tid;
    float4 v = ((const float4*)x)[i];
    union { unsigned short u[4]; uint2 v2; } o;
    o.u[0] = f2bf(v.x); o.u[1] = f2bf(v.y); o.u[2] = f2bf(v.z); o.u[3] = f2bf(v.w);
    ((uint2*)X16)[i] = o.v2;
    return;
  }
  const int tx = tid & 31, ty = tid >> 5;
  if (bid < 17408) {                      // ---- W_QKV transpose + corrections
    int t = bid - 8192;
    int k0 = (t & 63) * 32, n0 = (t >> 6) * 32;
    const float* src; int nboff;
    if (n0 < 1536)      { src = WQ; nboff = n0; }
    else if (n0 < 3072) { src = WK; nboff = n0 - 1536; }
    else                { src = WV; nboff = n0 - 3072; }
#pragma unroll
    for (int j = 0; j < 4; ++j) {
      int kk = ty + j * 8;
      tile[kk][tx] = src[(size_t)(k0 + kk) * 1536 + nboff + tx];
    }
    int corrsel = 0; const float* Fsrc = nullptr; const float* Psrc = nullptr;
    int h = 0, d0 = 0, fs = 0, koff = 0;
    if (n0 >= 1536) {
      bool isK = (n0 < 3072);
      int np0 = isK ? (n0 - 1536) : (n0 - 3072);
      if (np0 < 256) {
        if (k0 >= 256) { corrsel = 1; Fsrc = isK ? FK0 : FV0; Psrc = isK ? PK0 : PV0;
                         h = np0 >> 6; d0 = np0 & 63; fs = 32; koff = k0 - 256; }
      } else if (np0 < 768) {
        if (k0 >= 1024) { corrsel = 1; Fsrc = isK ? FK1 : FV1; Psrc = isK ? PK1 : PV1;
                          h = (np0 - 256) >> 6; d0 = (np0 - 256) & 63; fs = 64; koff = k0 - 1024; }
      }
    }
    if (corrsel) {
      Fs[tid >> 3][tid & 7] = Fsrc[(size_t)(koff + (tid >> 3)) * fs + h * 8 + (tid & 7)];
      Ps[tid >> 5][tid & 31] = Psrc[h * 512 + (tid >> 5) * 64 + d0 + (tid & 31)];
    }
    __syncthreads();
#pragma unroll
    for (int j = 0; j < 4; ++j) {
      int nn = ty + j * 8;
      float v = tile[tx][nn];
      if (corrsel) {
        float c = 0.f;
#pragma unroll
        for (int r = 0; r < 8; ++r) c += Fs[tx][r] * Ps[r][nn];
        v += c;
      }
      WTQKV[(size_t)(n0 + nn) * 2048 + k0 + tx] = f2bf(v);
    }
  } else {                                // ---- W_O transpose
    int t = bid - 17408;
    int k0 = (t % 48) * 32, n0 = (t / 48) * 32;
#pragma unroll
    for (int j = 0; j < 4; ++j)
      tile[ty + j * 8][tx] = WO[(size_t)(k0 + ty + j * 8) * 2048 + n0 + tx];
    __syncthreads();
#pragma unroll
    for (int j = 0; j < 4; ++j)
      WTO[(size_t)(n0 + ty + j * 8) * 1536 + k0 + tx] = f2bf(tile[tx][ty + j * 8]);
  }
}

// ---------------- 4. QKV GEMM: 256x256 tile, BK=32, triple-buffer pipeline --
// A = X16 [4096][2048] bf16 row-major; Bt = WTQKV [4608][2048]; C bf16 [4096][4608].
// 512 threads = 8 waves (2M x 4N); per-wave C = 128x64 = 8x4 fp32x4 frags.
// LDS layout per 256x32 tile: 128-byte lines (2 rows x 4 k-groups of 8 bf16),
// slot = ((row&1)*4 + kgroup) ^ (line&7)  -> conflict-free ds_read_b128
// (distinct slots within every 8-lane group; same criterion as R6's proven 0).
// Staging pre-swizzles the GLOBAL source per lane (LDS dest stays linear).
__device__ __forceinline__ int lds_off(int row, int kq) {
  int L = row >> 1;
  return L * 64 + ((((row & 1) << 2) | kq) ^ (L & 7)) * 8;
}

__global__ __launch_bounds__(512) void k_gemm1(const unsigned short* __restrict__ A,
                                               const unsigned short* __restrict__ Bt,
                                               unsigned short* __restrict__ C) {
  __shared__ unsigned short Ls[3][2][8192];   // [buf][A=0/B=1][256*32]
  const int tid = threadIdx.x;
  const int wave = tid >> 6, lane = tid & 63;
  const int qd = lane >> 4, ln = lane & 15;
  const int wr = wave >> 2, wc = wave & 3;
  // LPT dispatch: 240 long (Keff=2048) first, then 32 mid (1024), 16 short (256)
  int idx = blockIdx.x, bx, by, Keff;
  if (idx < 240)      { bx = 3 + idx % 15; by = idx / 15; Keff = 2048; }
  else if (idx < 272) { int t2 = idx - 240; bx = 1 + (t2 & 1); by = t2 >> 1; Keff = 1024; }
  else                { bx = 0; by = idx - 272; Keff = 256; }
  const int bm = by * 256, bn = bx * 256;
  const int NT = Keff >> 5;

  // staging source map (inverse of LDS swizzle): thread -> (line, slot)
  const int Lr = tid >> 3, sl = tid & 7;
  const int gg = sl ^ (Lr & 7);
  const int srow = 2 * Lr + (gg >> 2);        // 0..127 (load1 adds 128)
  const int skg = gg & 3;
  const unsigned short* gA = A + (size_t)(bm + srow) * 2048 + skg * 8;
  const unsigned short* gB = Bt + (size_t)(bn + srow) * 2048 + skg * 8;

  // ds_read fragment offsets (loop-invariant)
  int aoff[8], boff[4];
#pragma unroll
  for (int mi = 0; mi < 8; ++mi) aoff[mi] = lds_off(wr * 128 + mi * 16 + ln, qd);
#pragma unroll
  for (int ni = 0; ni < 4; ++ni) boff[ni] = lds_off(wc * 64 + ni * 16 + ln, qd);

  floatx4 acc[8][4];
#pragma unroll
  for (int i = 0; i < 8; ++i)
#pragma unroll
    for (int j = 0; j < 4; ++j) acc[i][j] = (floatx4){0.f, 0.f, 0.f, 0.f};

  // ---- prologue: stage tile0 -> buf0, tile1 -> buf1 (issue order = FIFO)
  {
    unsigned short* d = &Ls[0][0][wave * 512];
    gload_lds16(gA, d);                 gload_lds16(gA + 128 * 2048, d + 4096);
    d = &Ls[0][1][wave * 512];
    gload_lds16(gB, d);                 gload_lds16(gB + 128 * 2048, d + 4096);
    d = &Ls[1][0][wave * 512];
    gload_lds16(gA + 32, d);            gload_lds16(gA + 128 * 2048 + 32, d + 4096);
    d = &Ls[1][1][wave * 512];
    gload_lds16(gB + 32, d);            gload_lds16(gB + 128 * 2048 + 32, d + 4096);
  }
  asm volatile("s_waitcnt vmcnt(4)" ::: "memory");   // tile0 landed, tile1 in flight
  __builtin_amdgcn_s_barrier();

  int b = 0;
  for (int t = 0; t < NT; ++t) {
    const int b2 = (b >= 1) ? b - 1 : b + 2;         // (t+2)%3
    const unsigned short* la = &Ls[b][0][0];
    const unsigned short* lb = &Ls[b][1][0];
    const bool pf = (t + 2) < NT;
    const int k2 = (t + 2) << 5;
    // ---- phase 0: m-frags 0..3 x all n; stage t+2's A
    bf16x8 bfr[4], af[4];
#pragma unroll
    for (int ni = 0; ni < 4; ++ni) bfr[ni] = *(const bf16x8*)(lb + boff[ni]);
#pragma unroll
    for (int mi = 0; mi < 4; ++mi) af[mi] = *(const bf16x8*)(la + aoff[mi]);
    if (pf) {
      unsigned short* d = &Ls[b2][0][wave * 512];
      gload_lds16(gA + k2, d);
      gload_lds16(gA + 128 * 2048 + k2, d + 4096);
    }
    __builtin_amdgcn_s_barrier();
    __builtin_amdgcn_s_setprio(1);
#pragma unroll
    for (int mi = 0; mi < 4; ++mi)
#pragma unroll
      for (int ni = 0; ni < 4; ++ni)
        acc[mi][ni] = __builtin_amdgcn_mfma_f32_16x16x32_bf16(af[mi], bfr[ni], acc[mi][ni], 0, 0, 0);
    __builtin_amdgcn_s_setprio(0);
    __builtin_amdgcn_s_barrier();
    // ---- phase 1: m-frags 4..7 x all n; stage t+2's B
#pragma unroll
    for (int mi = 0; mi < 4; ++mi) af[mi] = *(const bf16x8*)(la + aoff[4 + mi]);
    if (pf) {
      unsigned short* d = &Ls[b2][1][wave * 512];
      gload_lds16(gB + k2, d);
      gload_lds16(gB + 128 * 2048 + k2, d + 4096);
    }
    __builtin_amdgcn_s_barrier();
    __builtin_amdgcn_s_setprio(1);
#pragma unroll
    for (int mi = 0; mi < 4; ++mi)
#pragma unroll
      for (int ni = 0; ni < 4; ++ni)
        acc[4 + mi][ni] = __builtin_amdgcn_mfma_f32_16x16x32_bf16(af[mi], bfr[ni], acc[4 + mi][ni], 0, 0, 0);
    __builtin_amdgcn_s_setprio(0);
    if (t + 1 < NT) {
      // tile-boundary: retire t+1's 4 loads (t+2's stay in flight); wait must
      // precede the barrier so every wave's slice is published before reads.
      if (pf) asm volatile("s_waitcnt vmcnt(4)" ::: "memory");
      else    asm volatile("s_waitcnt vmcnt(0)" ::: "memory");
      __builtin_amdgcn_s_barrier();
    }
    b = (b == 2) ? 0 : b + 1;
  }
  // ---- epilogue
#pragma unroll
  for (int mi = 0; mi < 8; ++mi)
#pragma unroll
    for (int r = 0; r < 4; ++r) {
      size_t row = (size_t)(bm + wr * 128 + mi * 16 + qd * 4 + r);
#pragma unroll
      for (int ni = 0; ni < 4; ++ni) {
        int col = bn + wc * 64 + ni * 16 + ln;
        C[row * 4608 + col] = f2bf(acc[mi][ni][r]);
      }
    }
}

// ---------------- 6. out GEMM BK=64, Keff per column block, LPT dispatch ----
// MODE 1: out (N=2048, 16 cols: long bx8..15, mid bx2..7, short bx0..1)
template <bool OUT_BF16, int MODE>
__global__ __launch_bounds__(256) void k_gemm_bt(const unsigned short* __restrict__ A,
                                                 const unsigned short* __restrict__ Bt,
                                                 void* __restrict__ C, int M, int N, int K) {
  __shared__ unsigned short As[128 * 64];
  __shared__ unsigned short Bs[128 * 64];
  const int tid = threadIdx.x;
  const int wave = tid >> 6, lane = tid & 63;
  const int qd = lane >> 4, ln = lane & 15;
  int idx = blockIdx.x, bx, by;
  if (MODE == 0) {
    if (idx < 960)       { bx = 6 + idx % 30; by = idx / 30; }
    else if (idx < 1088) { int t = idx - 960; bx = 2 + (t & 3); by = t >> 2; }
    else                 { int t = idx - 1088; bx = t & 1; by = t >> 1; }
  } else {
    if (idx < 256)       { bx = 8 + (idx & 7); by = idx >> 3; }
    else if (idx < 448)  { int t = idx - 256; bx = 2 + t % 6; by = t / 6; }
    else                 { int t = idx - 448; bx = t & 1; by = t >> 1; }
  }
  const int bm = by * 128, bn = bx * 128;
  const int wr = wave >> 1, wc = wave & 1;
  int Keff;
  if (MODE == 0) Keff = (bn < 256) ? 256 : (bn < 768 ? 1024 : 2048);
  else           Keff = (bn < 256) ? 256 : (bn < 1024 ? 768 : 1536);
  floatx4 acc[4][4];
#pragma unroll
  for (int i = 0; i < 4; ++i)
#pragma unroll
    for (int j = 0; j < 4; ++j) acc[i][j] = (floatx4){0.f, 0.f, 0.f, 0.f};
  const int rl = lane >> 3;                        // row mod 8
  const int sg = (lane & 7) ^ rl;                  // swizzled source group
  const unsigned short* gA = A + (size_t)(bm + wave * 32 + rl) * K + sg * 8;
  const unsigned short* gB = Bt + (size_t)(bn + wave * 32 + rl) * K + sg * 8;
  unsigned short* lA = As + wave * 2048;
  unsigned short* lB = Bs + wave * 2048;
  const int l7 = ln & 7;
  for (int k0 = 0; k0 < Keff; k0 += 64) {
    __syncthreads();
#pragma unroll
    for (int i = 0; i < 4; ++i) {
      gload_lds16(gA + (size_t)8 * i * K + k0, lA + i * 512);
      gload_lds16(gB + (size_t)8 * i * K + k0, lB + i * 512);
    }
    __syncthreads();
#pragma unroll
    for (int h = 0; h < 2; ++h) {
      bf16x8 af[4], bfr[4];
#pragma unroll
      for (int mi = 0; mi < 4; ++mi)
        af[mi] = *(const bf16x8*)(As + (wr * 64 + mi * 16 + ln) * 64 + ((h * 4 + qd) ^ l7) * 8);
#pragma unroll
      for (int ni = 0; ni < 4; ++ni)
        bfr[ni] = *(const bf16x8*)(Bs + (wc * 64 + ni * 16 + ln) * 64 + ((h * 4 + qd) ^ l7) * 8);
#pragma unroll
      for (int mi = 0; mi < 4; ++mi)
#pragma unroll
        for (int ni = 0; ni < 4; ++ni)
          acc[mi][ni] = __builtin_amdgcn_mfma_f32_16x16x32_bf16(af[mi], bfr[ni], acc[mi][ni], 0, 0, 0);
    }
  }
#pragma unroll
  for (int mi = 0; mi < 4; ++mi)
#pragma unroll
    for (int r = 0; r < 4; ++r) {
      int row = bm + wr * 64 + mi * 16 + qd * 4 + r;
#pragma unroll
      for (int ni = 0; ni < 4; ++ni) {
        int col = bn + wc * 64 + ni * 16 + ln;
        if (OUT_BF16)
          ((unsigned short*)C)[(size_t)row * N + col] = f2bf(acc[mi][ni][r]);
        else
          ((float*)C)[(size_t)row * N + col] = acc[mi][ni][r];
      }
    }
}

// ---------------- 4b. V transpose: VT[b][d(1536)][T] from QKV cols 3072+ ----
__global__ void k_transpose_v(const unsigned short* __restrict__ QKV,
                              unsigned short* __restrict__ VT) {
  __shared__ unsigned short t[64 * 65];
  const int tt = blockIdx.x * 64, dt = blockIdx.y * 64, b = blockIdx.z;
  const int tid = threadIdx.x;
  const int r = tid >> 3, c0 = (tid & 7) * 8;
#pragma unroll
  for (int i = 0; i < 2; ++i) {
    int tok = r + i * 32;
    union { uint4 v; unsigned short u[8]; } vv;
    vv.v = *(const uint4*)(QKV + (size_t)(b * 1024 + tt + tok) * 4608 + 3072 + dt + c0);
#pragma unroll
    for (int j = 0; j < 8; ++j) t[tok * 65 + c0 + j] = vv.u[j];
  }
  __syncthreads();
#pragma unroll
  for (int i = 0; i < 2; ++i) {
    int d = r + i * 32;
    union { uint4 v; unsigned short u[8]; } vv;
#pragma unroll
    for (int j = 0; j < 8; ++j) vv.u[j] = t[(c0 + j) * 65 + d];
    *(uint4*)(VT + ((size_t)b * 1536 + dt + d) * 1024 + tt + c0) = vv.v;
  }
}

// ---------------- 5. causal flash attention, 128q x 128k tiles --------------
// grid (8 qtiles [reversed], 24 heads, 4 batch), block 256 = 4 waves.
// Wave: 2 q-frags (16 rows, 64 apart). No-max exp2 softmax, deferred l.
// Diagonal tile: frag0 computes keys [0,64) only; frag1 masks keys >= 64.
#define LDP 136
__global__ __launch_bounds__(256) void k_attn(const unsigned short* __restrict__ QKV,
                                              const unsigned short* __restrict__ VT,
                                              unsigned short* __restrict__ Oout) {
  __shared__ unsigned short Ks[128 * 64];     // [key][d], 8-grp XOR swizzle
  __shared__ unsigned short VTs[64 * 128];    // [d][key], 16-grp XOR swizzle
  __shared__ unsigned short Pl[4][16 * LDP];  // wave-private P staging
  const int tid = threadIdx.x;
  const int wave = tid >> 6, lane = tid & 63;
  const int qd = lane >> 4, ln = lane & 15;
  const int qb = (int)gridDim.x - 1 - (int)blockIdx.x;   // big blocks first
  const int gh = blockIdx.y, b = blockIdx.z;
  const int T = 1024, LD = 4608;
  const size_t rowbase = (size_t)b * T * LD;
  const int qcol = 64 * gh, kcol = 1536 + 64 * gh;
  const unsigned short* VTg = VT + ((size_t)b * 1536 + 64 * gh) * 1024;
  const float SCALE = 0.18033688f;  // 1/sqrt(64) * log2(e)
  const int q0 = qb * 128 + wave * 16;       // frag j adds j*64

  bf16x8 aq[2][2];
#pragma unroll
  for (int j = 0; j < 2; ++j) {
    const unsigned short* qp = QKV + rowbase + (size_t)(q0 + j * 64 + ln) * LD + qcol;
    aq[j][0] = *(const bf16x8*)(qp + qd * 8);
    aq[j][1] = *(const bf16x8*)(qp + 32 + qd * 8);
  }
  floatx4 Oacc[2][4];
#pragma unroll
  for (int j = 0; j < 2; ++j)
#pragma unroll
    for (int i = 0; i < 4; ++i) Oacc[j][i] = (floatx4){0.f, 0.f, 0.f, 0.f};
  float l_lane[2] = {0.f, 0.f};

  // K staging: wave stages rows [wave*32, +32) (4 gloads x 8 rows)
  const int rk = lane >> 3;                   // 0..7
  const int gk = ((lane & 7) ^ rk) * 8;       // swizzled source group (8-grp)
  const unsigned short* gK = QKV + rowbase + (size_t)(wave * 32 + rk) * LD + kcol + gk;
  unsigned short* lK = Ks + wave * 32 * 64;
  // VT staging: wave stages d-rows [wave*16, +16) (4 gloads x 4 rows x 128 c)
  const int rv = lane >> 4;                   // 0..3
  const int cv = lane & 15;
  unsigned short* lV = VTs + wave * 16 * 128;
  const unsigned short* gVrow[4];
  int gvcol[4];
#pragma unroll
  for (int i = 0; i < 4; ++i) {
    int d = wave * 16 + 4 * i + rv;
    gVrow[i] = VTg + (size_t)d * 1024;
    gvcol[i] = (cv ^ (4 * i + rv)) * 8;       // 16-grp swizzle by d&15
  }
  const int l7 = ln & 7;

  for (int jt = 0; jt <= qb; ++jt) {
    const int jk = jt * 128;
    const bool diag = (jt == qb);
    __syncthreads();
#pragma unroll
    for (int i = 0; i < 4; ++i) {
      gload_lds16(gK + (size_t)(jk + 8 * i) * LD, lK + i * 512);
      gload_lds16(gVrow[i] + jk + gvcol[i], lV + i * 512);
    }
    __syncthreads();

#pragma unroll
    for (int j = 0; j < 2; ++j) {
      const bool dj0 = diag && (j == 0);
      const int hmax = dj0 ? 4 : 8;
      // S^T = K Q^T : A = K[key][d] (frag h = keys h*16..+16), B = Q
      floatx4 Sc[8];
#pragma unroll
      for (int h = 0; h < 8; ++h) {
        if (h >= hmax) continue;
        Sc[h] = (floatx4){0.f, 0.f, 0.f, 0.f};
        bf16x8 a0 = *(const bf16x8*)(Ks + (h * 16 + ln) * 64 + (qd ^ l7) * 8);
        bf16x8 a1 = *(const bf16x8*)(Ks + (h * 16 + ln) * 64 + ((4 + qd) ^ l7) * 8);
        Sc[h] = __builtin_amdgcn_mfma_f32_16x16x32_bf16(a0, aq[j][0], Sc[h], 0, 0, 0);
        Sc[h] = __builtin_amdgcn_mfma_f32_16x16x32_bf16(a1, aq[j][1], Sc[h], 0, 0, 0);
      }
      const int qrow = q0 + j * 64 + ln;
      unsigned short* pw = Pl[wave];
#pragma unroll
      for (int h = 0; h < 8; ++h) {
        if (h >= hmax) continue;
        union { unsigned short u[4]; uint2 v; } pk;
#pragma unroll
        for (int r = 0; r < 4; ++r) {
          float v = fminf(Sc[h][r] * SCALE, 80.f);
          float p = __builtin_amdgcn_exp2f(v);
          if (diag && (j == 0 || h >= 4)) {
            int key = jk + h * 16 + qd * 4 + r;
            if (key > qrow) p = 0.f;
          }
          l_lane[j] += p;
          pk.u[r] = f2bf(p);
        }
        *(uint2*)(pw + ln * LDP + h * 16 + qd * 4) = pk.v;
      }
      __asm__ volatile("s_waitcnt lgkmcnt(0)" ::: "memory");
      const int smax = dj0 ? 2 : 4;
      bf16x8 pa[4];
#pragma unroll
      for (int s = 0; s < 4; ++s) {
        if (s >= smax) continue;
        pa[s] = *(const bf16x8*)(pw + ln * LDP + s * 32 + qd * 8);
      }
#pragma unroll
      for (int nc = 0; nc < 4; ++nc) {
        const int d = nc * 16 + ln;
#pragma unroll
        for (int s = 0; s < 4; ++s) {
          if (s >= smax) continue;
          bf16x8 bv = *(const bf16x8*)(VTs + d * 128 + (((s * 4 + qd) ^ ln) & 15) * 8);
          Oacc[j][nc] = __builtin_amdgcn_mfma_f32_16x16x32_bf16(pa[s], bv, Oacc[j][nc], 0, 0, 0);
        }
      }
    }
  }
  // l: sum the 4 qd-groups per ln, then normalize + store
#pragma unroll
  for (int j = 0; j < 2; ++j) {
    float l = l_lane[j];
    l += __shfl_xor(l, 16, 64);
    l += __shfl_xor(l, 32, 64);
#pragma unroll
    for (int r = 0; r < 4; ++r) {
      float inv = 1.0f / __shfl(l, qd * 4 + r, 64);
      size_t row = (size_t)b * T + q0 + j * 64 + qd * 4 + r;
#pragma unroll
      for (int nc = 0; nc < 4; ++nc)
        Oout[row * 1536 + 64 * gh + nc * 16 + ln] = f2bf(Oacc[j][nc][r] * inv);
    }
  }
}

// ---------------------------------------------------------------------------
extern "C" void kernel_launch(void* const* d_in, const int* in_sizes, int n_in,
                              void* d_out, int out_size, void* d_ws, size_t ws_size,
                              hipStream_t stream) {
  (void)in_sizes; (void)n_in; (void)out_size; (void)ws_size;
  const float* x   = (const float*)d_in[0];
  const float* WQ  = (const float*)d_in[1];
  const float* WK  = (const float*)d_in[2];
  const float* WV  = (const float*)d_in[3];
  const float* WO  = (const float*)d_in[4];
  const float* FK0 = (const float*)d_in[5];
  const float* PK0 = (const float*)d_in[6];
  const float* FV0 = (const float*)d_in[7];
  const float* PV0 = (const float*)d_in[8];
  const float* FK1 = (const float*)d_in[9];
  const float* PK1 = (const float*)d_in[10];
  const float* FV1 = (const float*)d_in[11];
  const float* PV1 = (const float*)d_in[12];

  char* ws = (char*)d_ws;
  unsigned short* X16   = (unsigned short*)(ws + 0);          // 16 MB (dead after GEMM1)
  unsigned short* VTb   = X16;                                 // VT aliases X16
  unsigned short* WTQKV = (unsigned short*)(ws + 16777216);   // 18 MB
  unsigned short* QKV   = (unsigned short*)(ws + 35651584);   // 36 MB
  unsigned short* ATT   = (unsigned short*)(ws + 73400320);   // 12 MB
  unsigned short* WTO   = (unsigned short*)(ws + 85983232);   //  6 MB

  k_prep<<<20480, 256, 0, stream>>>(x, X16, WQ, WK, WV,
                                    FK0, PK0, FV0, PV0, FK1, PK1, FV1, PV1,
                                    WTQKV, WO, WTO);
  k_gemm1<<<288, 512, 0, stream>>>(X16, WTQKV, QKV);
  k_transpose_v<<<dim3(16, 24, 4), 256, 0, stream>>>(QKV, VTb);
  k_attn<<<dim3(8, 24, 4), 256, 0, stream>>>(QKV, VTb, ATT);
  k_gemm_bt<false, 1><<<512, 256, 0, stream>>>(ATT, WTO, d_out, 4096, 2048, 1536);
}